// Round 5
// baseline (856.239 us; speedup 1.0000x reference)
//
#include <hip/hip_runtime.h>

#define SEQ   2048
#define DK    64
#define QBLK  64
#define KVBLK 64
#define NTILE (SEQ / KVBLK)
#define PITCH 72   // bf16 elements; 144B rows, 16B-aligned

typedef __attribute__((ext_vector_type(8))) __bf16 bf16x8;
typedef __attribute__((ext_vector_type(4))) __bf16 bf16x4;
typedef __attribute__((ext_vector_type(2))) __bf16 bf16x2;
typedef __attribute__((ext_vector_type(4))) float  f32x4;
typedef __attribute__((ext_vector_type(4))) int    i32x4;

// 16-lane reductions via DPP row_ror (VALU only — no LDS pipe, unlike
// __shfl_xor which compiles to ds_swizzle and serialized against staging
// traffic + lgkmcnt barrier drains). row == 16 lanes == our reduce group.
template<int CTRL>
__device__ __forceinline__ float dpp_ror(float v) {
  int i = __builtin_bit_cast(int, v);
  int r = __builtin_amdgcn_update_dpp(i, i, CTRL, 0xf, 0xf, false);
  return __builtin_bit_cast(float, r);
}
__device__ __forceinline__ float grp16_max(float v) {
  v = fmaxf(v, dpp_ror<0x128>(v));   // row_ror:8
  v = fmaxf(v, dpp_ror<0x124>(v));   // row_ror:4
  v = fmaxf(v, dpp_ror<0x122>(v));   // row_ror:2
  v = fmaxf(v, dpp_ror<0x121>(v));   // row_ror:1
  return v;
}
__device__ __forceinline__ float grp16_sum(float v) {
  v += dpp_ror<0x128>(v);
  v += dpp_ror<0x124>(v);
  v += dpp_ror<0x122>(v);
  v += dpp_ror<0x121>(v);
  return v;
}

// LDS-only barrier: global loads (mask/K/V prefetch) stay in flight across it.
__device__ __forceinline__ void block_sync_lds() {
  asm volatile("s_waitcnt lgkmcnt(0)" ::: "memory");
  __builtin_amdgcn_sched_barrier(0);
  __builtin_amdgcn_s_barrier();
  __builtin_amdgcn_sched_barrier(0);
}

// Flash attention, 4 waves x 16 q-rows, KV tiles of 64.
// K staged at permuted row: Klds[j][d] = K[pi(j)][d], pi(j) = (j&15)*4 + (j>>4),
// so score col (nt*16+li) <-> kv = li*4+nt: mask loads int4, P writes b64,
// both in TRUE kv space; V staged unpermuted transposed (Vt[d][kv]) via
// paired bf16x2 b32 writes (conflict-free; replaces 16 conflicted b16 writes).
__global__ __launch_bounds__(256, 3)
void sdpa_fwd(const float* __restrict__ Q, const float* __restrict__ K,
              const float* __restrict__ V, const int* __restrict__ M,
              float* __restrict__ O)
{
  __shared__ __bf16 Klds[KVBLK][PITCH];
  __shared__ __bf16 Vt[DK][PITCH];
  __shared__ __bf16 Plds[4][16][PITCH];

  const int tid  = threadIdx.x;
  const int w    = tid >> 6;
  const int lane = tid & 63;
  const int g    = lane >> 4;
  const int li   = lane & 15;

  // XCD-aware bijective swizzle (1024 % 8 == 0)
  const int bid = blockIdx.x;
  const int blk = (bid & 7) * 128 + (bid >> 3);
  const int qb  = blk & (SEQ / QBLK - 1);
  const int bh  = blk >> 5;

  const float* Qp = Q + (size_t)bh * SEQ * DK;
  const float* Kp = K + (size_t)bh * SEQ * DK;
  const float* Vp = V + (size_t)bh * SEQ * DK;
  const int*   Mp = M + (size_t)bh * SEQ * SEQ;
  float*       Op = O + (size_t)bh * SEQ * DK;

  const int q0 = qb * QBLK + w * 16;

  // K staging: thread covers K row sk, cols [sd, sd+16)
  const int sk = tid >> 2;
  const int sd = (tid & 3) * 16;
  const int sj = ((sk & 3) << 4) | (sk >> 2);   // pi^{-1}(sk)
  // V staging: thread covers rows {vk, vk+1}, cols [vd, vd+8)
  const int vk = (tid & 31) * 2;
  const int vd = (tid >> 5) * 8;

  // ---- Q fragments (1/8 and log2e folded; softmax in exp2) ----
  bf16x8 qfrag[2];
  {
    const float qs = 0.125f * 1.44269504088896340736f;
    const float* qr = Qp + (size_t)(q0 + li) * DK + g * 8;
    #pragma unroll
    for (int h2 = 0; h2 < 2; ++h2) {
      f32x4 a = *(const f32x4*)(qr + h2 * 32);
      f32x4 b = *(const f32x4*)(qr + h2 * 32 + 4);
      bf16x8 f;
      #pragma unroll
      for (int e = 0; e < 4; ++e) { f[e] = (__bf16)(a[e] * qs); f[4 + e] = (__bf16)(b[e] * qs); }
      qfrag[h2] = f;
    }
  }

  f32x4 acc[4];
  #pragma unroll
  for (int c = 0; c < 4; ++c) acc[c] = (f32x4){0.f, 0.f, 0.f, 0.f};
  float m_r[4], l_r[4];
  #pragma unroll
  for (int r = 0; r < 4; ++r) { m_r[r] = -__builtin_inff(); l_r[r] = 0.f; }

  f32x4 kA[4], vA[4];
  i32x4 mA[4], mB[4];   // mask ping-pong: depth-2 pipeline

  // ---- prologue: K/V tile 0; mask tiles 0 and 1 ----
  {
    const float* ks  = Kp + (size_t)sk * DK + sd;
    const float* vs0 = Vp + (size_t)vk * DK + vd;
    const float* vs1 = Vp + (size_t)(vk + 1) * DK + vd;
    #pragma unroll
    for (int i = 0; i < 4; ++i) kA[i] = *(const f32x4*)(ks + 4 * i);
    vA[0] = *(const f32x4*)vs0; vA[1] = *(const f32x4*)(vs0 + 4);
    vA[2] = *(const f32x4*)vs1; vA[3] = *(const f32x4*)(vs1 + 4);
    #pragma unroll
    for (int r = 0; r < 4; ++r) {
      const size_t mrow = (size_t)(q0 + 4 * g + r) * SEQ + li * 4;
      mA[r] = *(const i32x4*)(Mp + mrow);
      mB[r] = *(const i32x4*)(Mp + mrow + KVBLK);
    }
  }

  auto body = [&](int kt, i32x4 (&mc)[4]) {
    block_sync_lds();   // WAR: prev tile's LDS reads complete

    // ---- stage regs -> LDS ----
    {
      bf16x8 klo, khi;
      #pragma unroll
      for (int e = 0; e < 4; ++e) {
        klo[e] = (__bf16)kA[0][e]; klo[4 + e] = (__bf16)kA[1][e];
        khi[e] = (__bf16)kA[2][e]; khi[4 + e] = (__bf16)kA[3][e];
      }
      *(bf16x8*)&Klds[sj][sd]     = klo;
      *(bf16x8*)&Klds[sj][sd + 8] = khi;
      #pragma unroll
      for (int j = 0; j < 4; ++j) {
        bf16x2 p0; p0[0] = (__bf16)vA[0][j]; p0[1] = (__bf16)vA[2][j];
        bf16x2 p1; p1[0] = (__bf16)vA[1][j]; p1[1] = (__bf16)vA[3][j];
        *(bf16x2*)&Vt[vd + j][vk]     = p0;
        *(bf16x2*)&Vt[vd + 4 + j][vk] = p1;
      }
    }

    // consume this tile's mask; refill buffers (loads stay in flight)
    i32x4 msk[4];
    #pragma unroll
    for (int r = 0; r < 4; ++r) msk[r] = mc[r];
    {
      const int tm = (kt + 2 < NTILE) ? kt + 2 : 0;
      #pragma unroll
      for (int r = 0; r < 4; ++r)
        mc[r] = *(const i32x4*)(Mp + (size_t)(q0 + 4 * g + r) * SEQ + tm * KVBLK + li * 4);
      const int tn = (kt + 1 < NTILE) ? kt + 1 : 0;
      const float* ks  = Kp + (size_t)(tn * KVBLK + sk) * DK + sd;
      const float* vs0 = Vp + (size_t)(tn * KVBLK + vk) * DK + vd;
      const float* vs1 = Vp + (size_t)(tn * KVBLK + vk + 1) * DK + vd;
      #pragma unroll
      for (int i = 0; i < 4; ++i) kA[i] = *(const f32x4*)(ks + 4 * i);
      vA[0] = *(const f32x4*)vs0; vA[1] = *(const f32x4*)(vs0 + 4);
      vA[2] = *(const f32x4*)vs1; vA[3] = *(const f32x4*)(vs1 + 4);
    }

    block_sync_lds();   // staged tile visible; global loads still in flight

    // ---- QK^T ----
    f32x4 st[4];
    __builtin_amdgcn_s_setprio(1);
    #pragma unroll
    for (int nt = 0; nt < 4; ++nt) {
      bf16x8 b0 = *(const bf16x8*)&Klds[nt * 16 + li][g * 8];
      bf16x8 b1 = *(const bf16x8*)&Klds[nt * 16 + li][32 + g * 8];
      f32x4 s = (f32x4){0.f, 0.f, 0.f, 0.f};
      s = __builtin_amdgcn_mfma_f32_16x16x32_bf16(qfrag[0], b0, s, 0, 0, 0);
      s = __builtin_amdgcn_mfma_f32_16x16x32_bf16(qfrag[1], b1, s, 0, 0, 0);
      st[nt] = s;
    }
    __builtin_amdgcn_s_setprio(0);

    // ---- mask + online softmax (DPP reduces); st[nt][r] = kv li*4+nt ----
    #pragma unroll
    for (int r = 0; r < 4; ++r) {
      float s0 = msk[r].x ? -1e9f : st[0][r];
      float s1 = msk[r].y ? -1e9f : st[1][r];
      float s2 = msk[r].z ? -1e9f : st[2][r];
      float s3 = msk[r].w ? -1e9f : st[3][r];
      float mx    = grp16_max(fmaxf(fmaxf(s0, s1), fmaxf(s2, s3)));
      float mnew  = fmaxf(m_r[r], mx);
      float alpha = __builtin_amdgcn_exp2f(m_r[r] - mnew);
      float p0 = __builtin_amdgcn_exp2f(s0 - mnew);
      float p1 = __builtin_amdgcn_exp2f(s1 - mnew);
      float p2 = __builtin_amdgcn_exp2f(s2 - mnew);
      float p3 = __builtin_amdgcn_exp2f(s3 - mnew);
      l_r[r] = l_r[r] * alpha + grp16_sum((p0 + p1) + (p2 + p3));
      m_r[r] = mnew;
      acc[0][r] *= alpha;
      acc[1][r] *= alpha;
      acc[2][r] *= alpha;
      acc[3][r] *= alpha;
      bf16x4 pk;
      pk[0] = (__bf16)p0; pk[1] = (__bf16)p1; pk[2] = (__bf16)p2; pk[3] = (__bf16)p3;
      *(bf16x4*)&Plds[w][4 * g + r][li * 4] = pk;
    }

    // wave-private P tile: writes land before fragment reads
    asm volatile("s_waitcnt lgkmcnt(0)" ::: "memory");
    __builtin_amdgcn_sched_barrier(0);

    // ---- PV ----
    bf16x8 pa0 = *(const bf16x8*)&Plds[w][li][g * 8];
    bf16x8 pa1 = *(const bf16x8*)&Plds[w][li][32 + g * 8];
    __builtin_amdgcn_s_setprio(1);
    #pragma unroll
    for (int dt = 0; dt < 4; ++dt) {
      bf16x8 v0 = *(const bf16x8*)&Vt[dt * 16 + li][g * 8];
      bf16x8 v1 = *(const bf16x8*)&Vt[dt * 16 + li][32 + g * 8];
      acc[dt] = __builtin_amdgcn_mfma_f32_16x16x32_bf16(pa0, v0, acc[dt], 0, 0, 0);
      acc[dt] = __builtin_amdgcn_mfma_f32_16x16x32_bf16(pa1, v1, acc[dt], 0, 0, 0);
    }
    __builtin_amdgcn_s_setprio(0);
  };

  // manual x2 unroll keeps the mask ping-pong statically indexed (rule #20)
  for (int kt = 0; kt < NTILE; kt += 2) {
    body(kt, mA);
    body(kt + 1, mB);
  }

  // ---- epilogue ----
  #pragma unroll
  for (int r = 0; r < 4; ++r) {
    float inv = 1.0f / l_r[r];
    float* orow = Op + (size_t)(q0 + 4 * g + r) * DK + li;
    #pragma unroll
    for (int dt = 0; dt < 4; ++dt)
      orow[dt * 16] = acc[dt][r] * inv;
  }
}

extern "C" void kernel_launch(void* const* d_in, const int* in_sizes, int n_in,
                              void* d_out, int out_size, void* d_ws, size_t ws_size,
                              hipStream_t stream) {
  const float* Q = (const float*)d_in[0];
  const float* K = (const float*)d_in[1];
  const float* V = (const float*)d_in[2];
  const int*   M = (const int*)d_in[3];
  float*       O = (float*)d_out;

  const int nblocks = 2 * 16 * (SEQ / QBLK);  // 1024
  sdpa_fwd<<<nblocks, 256, 0, stream>>>(Q, K, V, M, O);
}

// Round 7
// 761.150 us; speedup vs baseline: 1.1249x; 1.1249x over previous
//
#include <hip/hip_runtime.h>

#define SEQ   2048
#define DK    64
#define QBLK  64
#define KVBLK 64
#define NTILE (SEQ / KVBLK)
#define PITCH 72   // bf16 elements; 144B rows, 16B-aligned

typedef __attribute__((ext_vector_type(8))) __bf16 bf16x8;
typedef __attribute__((ext_vector_type(4))) __bf16 bf16x4;
typedef __attribute__((ext_vector_type(2))) __bf16 bf16x2;
typedef __attribute__((ext_vector_type(4))) float  f32x4;
typedef __attribute__((ext_vector_type(4))) int    i32x4;

// 16-lane reductions via DPP row_ror (pure VALU — keeps the shuffle off the
// LDS pipe, which ds_swizzle-based __shfl_xor would hit).
template<int CTRL>
__device__ __forceinline__ float dpp_ror(float v) {
  int i = __builtin_bit_cast(int, v);
  int r = __builtin_amdgcn_update_dpp(i, i, CTRL, 0xf, 0xf, false);
  return __builtin_bit_cast(float, r);
}
__device__ __forceinline__ float grp16_max(float v) {
  v = fmaxf(v, dpp_ror<0x128>(v));   // row_ror:8
  v = fmaxf(v, dpp_ror<0x124>(v));   // row_ror:4
  v = fmaxf(v, dpp_ror<0x122>(v));   // row_ror:2
  v = fmaxf(v, dpp_ror<0x121>(v));   // row_ror:1
  return v;
}
__device__ __forceinline__ float grp16_sum(float v) {
  v += dpp_ror<0x128>(v);
  v += dpp_ror<0x124>(v);
  v += dpp_ror<0x122>(v);
  v += dpp_ror<0x121>(v);
  return v;
}

// LDS-only barrier: global loads (mask/K/V prefetch) stay in flight across it.
__device__ __forceinline__ void block_sync_lds() {
  asm volatile("s_waitcnt lgkmcnt(0)" ::: "memory");
  __builtin_amdgcn_sched_barrier(0);
  __builtin_amdgcn_s_barrier();
  __builtin_amdgcn_sched_barrier(0);
}

// Flash attention, 4 waves x 16 q-rows, KV tiles of 64.
// K staged at permuted row: Klds[j][d] = K[pi(j)][d], pi(j) = (j&15)*4 + (j>>4),
// so score col (nt*16+li) <-> kv = li*4+nt: mask loads int4, P writes b64,
// both in TRUE kv space; V staged unpermuted transposed (Vt[d][kv]) via
// paired bf16x2 b32 writes (conflict-free).
// Depth-1 register pipeline for mask/K/V: issued mid-iteration t, consumed
// at t+1; raw LDS barriers keep them in flight across the sync points.
// launch_bounds(256,2): do NOT force 3 waves/EU — R5 showed the ~170-VGPR
// cap spills the live set; let the allocator land naturally.
__global__ __launch_bounds__(256, 2)
void sdpa_fwd(const float* __restrict__ Q, const float* __restrict__ K,
              const float* __restrict__ V, const int* __restrict__ M,
              float* __restrict__ O)
{
  __shared__ __bf16 Klds[KVBLK][PITCH];
  __shared__ __bf16 Vt[DK][PITCH];
  __shared__ __bf16 Plds[4][16][PITCH];

  const int tid  = threadIdx.x;
  const int w    = tid >> 6;
  const int lane = tid & 63;
  const int g    = lane >> 4;
  const int li   = lane & 15;

  // XCD-aware bijective swizzle (1024 % 8 == 0)
  const int bid = blockIdx.x;
  const int blk = (bid & 7) * 128 + (bid >> 3);
  const int qb  = blk & (SEQ / QBLK - 1);
  const int bh  = blk >> 5;

  const float* Qp = Q + (size_t)bh * SEQ * DK;
  const float* Kp = K + (size_t)bh * SEQ * DK;
  const float* Vp = V + (size_t)bh * SEQ * DK;
  const int*   Mp = M + (size_t)bh * SEQ * SEQ;
  float*       Op = O + (size_t)bh * SEQ * DK;

  const int q0 = qb * QBLK + w * 16;

  // K staging: thread covers K row sk, cols [sd, sd+16)
  const int sk = tid >> 2;
  const int sd = (tid & 3) * 16;
  const int sj = ((sk & 3) << 4) | (sk >> 2);   // pi^{-1}(sk)
  // V staging: thread covers rows {vk, vk+1}, cols [vd, vd+8)
  const int vk = (tid & 31) * 2;
  const int vd = (tid >> 5) * 8;

  // ---- Q fragments (1/8 and log2e folded; softmax in exp2) ----
  bf16x8 qfrag[2];
  {
    const float qs = 0.125f * 1.44269504088896340736f;
    const float* qr = Qp + (size_t)(q0 + li) * DK + g * 8;
    #pragma unroll
    for (int h2 = 0; h2 < 2; ++h2) {
      f32x4 a = *(const f32x4*)(qr + h2 * 32);
      f32x4 b = *(const f32x4*)(qr + h2 * 32 + 4);
      bf16x8 f;
      #pragma unroll
      for (int e = 0; e < 4; ++e) { f[e] = (__bf16)(a[e] * qs); f[4 + e] = (__bf16)(b[e] * qs); }
      qfrag[h2] = f;
    }
  }

  f32x4 acc[4];
  #pragma unroll
  for (int c = 0; c < 4; ++c) acc[c] = (f32x4){0.f, 0.f, 0.f, 0.f};
  float m_r[4], l_r[4];
  #pragma unroll
  for (int r = 0; r < 4; ++r) { m_r[r] = -__builtin_inff(); l_r[r] = 0.f; }

  f32x4 kA[4], vA[4];
  i32x4 mA[4];          // depth-1 mask pipeline

  // ---- prologue: K/V/mask tile 0 ----
  {
    const float* ks  = Kp + (size_t)sk * DK + sd;
    const float* vs0 = Vp + (size_t)vk * DK + vd;
    const float* vs1 = Vp + (size_t)(vk + 1) * DK + vd;
    #pragma unroll
    for (int i = 0; i < 4; ++i) kA[i] = *(const f32x4*)(ks + 4 * i);
    vA[0] = *(const f32x4*)vs0; vA[1] = *(const f32x4*)(vs0 + 4);
    vA[2] = *(const f32x4*)vs1; vA[3] = *(const f32x4*)(vs1 + 4);
    #pragma unroll
    for (int r = 0; r < 4; ++r)
      mA[r] = *(const i32x4*)(Mp + (size_t)(q0 + 4 * g + r) * SEQ + li * 4);
  }

  for (int kt = 0; kt < NTILE; ++kt) {
    block_sync_lds();   // WAR: prev tile's LDS reads complete

    // ---- stage regs -> LDS ----
    {
      bf16x8 klo, khi;
      #pragma unroll
      for (int e = 0; e < 4; ++e) {
        klo[e] = (__bf16)kA[0][e]; klo[4 + e] = (__bf16)kA[1][e];
        khi[e] = (__bf16)kA[2][e]; khi[4 + e] = (__bf16)kA[3][e];
      }
      *(bf16x8*)&Klds[sj][sd]     = klo;
      *(bf16x8*)&Klds[sj][sd + 8] = khi;
      #pragma unroll
      for (int j = 0; j < 4; ++j) {
        bf16x2 p0; p0[0] = (__bf16)vA[0][j]; p0[1] = (__bf16)vA[2][j];
        bf16x2 p1; p1[0] = (__bf16)vA[1][j]; p1[1] = (__bf16)vA[3][j];
        *(bf16x2*)&Vt[vd + j][vk]     = p0;
        *(bf16x2*)&Vt[vd + 4 + j][vk] = p1;
      }
    }

    // consume this tile's mask; refill all depth-1 buffers with tile kt+1
    // (loads stay in flight across block_sync_lds; consumed next iteration)
    i32x4 msk[4];
    #pragma unroll
    for (int r = 0; r < 4; ++r) msk[r] = mA[r];
    {
      const int tn = (kt + 1 < NTILE) ? kt + 1 : 0;   // clamped, branch-free
      #pragma unroll
      for (int r = 0; r < 4; ++r)
        mA[r] = *(const i32x4*)(Mp + (size_t)(q0 + 4 * g + r) * SEQ + tn * KVBLK + li * 4);
      const float* ks  = Kp + (size_t)(tn * KVBLK + sk) * DK + sd;
      const float* vs0 = Vp + (size_t)(tn * KVBLK + vk) * DK + vd;
      const float* vs1 = Vp + (size_t)(tn * KVBLK + vk + 1) * DK + vd;
      #pragma unroll
      for (int i = 0; i < 4; ++i) kA[i] = *(const f32x4*)(ks + 4 * i);
      vA[0] = *(const f32x4*)vs0; vA[1] = *(const f32x4*)(vs0 + 4);
      vA[2] = *(const f32x4*)vs1; vA[3] = *(const f32x4*)(vs1 + 4);
    }

    block_sync_lds();   // staged tile visible; global loads still in flight

    // ---- QK^T ----
    f32x4 st[4];
    #pragma unroll
    for (int nt = 0; nt < 4; ++nt) {
      bf16x8 b0 = *(const bf16x8*)&Klds[nt * 16 + li][g * 8];
      bf16x8 b1 = *(const bf16x8*)&Klds[nt * 16 + li][32 + g * 8];
      f32x4 s = (f32x4){0.f, 0.f, 0.f, 0.f};
      s = __builtin_amdgcn_mfma_f32_16x16x32_bf16(qfrag[0], b0, s, 0, 0, 0);
      s = __builtin_amdgcn_mfma_f32_16x16x32_bf16(qfrag[1], b1, s, 0, 0, 0);
      st[nt] = s;
    }

    // ---- mask + online softmax (DPP reduces); st[nt][r] = kv li*4+nt ----
    #pragma unroll
    for (int r = 0; r < 4; ++r) {
      float s0 = msk[r].x ? -1e9f : st[0][r];
      float s1 = msk[r].y ? -1e9f : st[1][r];
      float s2 = msk[r].z ? -1e9f : st[2][r];
      float s3 = msk[r].w ? -1e9f : st[3][r];
      float mx    = grp16_max(fmaxf(fmaxf(s0, s1), fmaxf(s2, s3)));
      float mnew  = fmaxf(m_r[r], mx);
      float alpha = __builtin_amdgcn_exp2f(m_r[r] - mnew);
      float p0 = __builtin_amdgcn_exp2f(s0 - mnew);
      float p1 = __builtin_amdgcn_exp2f(s1 - mnew);
      float p2 = __builtin_amdgcn_exp2f(s2 - mnew);
      float p3 = __builtin_amdgcn_exp2f(s3 - mnew);
      l_r[r] = l_r[r] * alpha + grp16_sum((p0 + p1) + (p2 + p3));
      m_r[r] = mnew;
      acc[0][r] *= alpha;
      acc[1][r] *= alpha;
      acc[2][r] *= alpha;
      acc[3][r] *= alpha;
      bf16x4 pk;
      pk[0] = (__bf16)p0; pk[1] = (__bf16)p1; pk[2] = (__bf16)p2; pk[3] = (__bf16)p3;
      *(bf16x4*)&Plds[w][4 * g + r][li * 4] = pk;
    }

    // wave-private P tile: writes land before fragment reads
    asm volatile("s_waitcnt lgkmcnt(0)" ::: "memory");
    __builtin_amdgcn_sched_barrier(0);

    // ---- PV ----
    bf16x8 pa0 = *(const bf16x8*)&Plds[w][li][g * 8];
    bf16x8 pa1 = *(const bf16x8*)&Plds[w][li][32 + g * 8];
    #pragma unroll
    for (int dt = 0; dt < 4; ++dt) {
      bf16x8 v0 = *(const bf16x8*)&Vt[dt * 16 + li][g * 8];
      bf16x8 v1 = *(const bf16x8*)&Vt[dt * 16 + li][32 + g * 8];
      acc[dt] = __builtin_amdgcn_mfma_f32_16x16x32_bf16(pa0, v0, acc[dt], 0, 0, 0);
      acc[dt] = __builtin_amdgcn_mfma_f32_16x16x32_bf16(pa1, v1, acc[dt], 0, 0, 0);
    }
  }

  // ---- epilogue ----
  #pragma unroll
  for (int r = 0; r < 4; ++r) {
    float inv = 1.0f / l_r[r];
    float* orow = Op + (size_t)(q0 + 4 * g + r) * DK + li;
    #pragma unroll
    for (int dt = 0; dt < 4; ++dt)
      orow[dt * 16] = acc[dt][r] * inv;
  }
}

extern "C" void kernel_launch(void* const* d_in, const int* in_sizes, int n_in,
                              void* d_out, int out_size, void* d_ws, size_t ws_size,
                              hipStream_t stream) {
  const float* Q = (const float*)d_in[0];
  const float* K = (const float*)d_in[1];
  const float* V = (const float*)d_in[2];
  const int*   M = (const int*)d_in[3];
  float*       O = (float*)d_out;

  const int nblocks = 2 * 16 * (SEQ / QBLK);  // 1024
  sdpa_fwd<<<nblocks, 256, 0, stream>>>(Q, K, V, M, O);
}

// Round 9
// 724.977 us; speedup vs baseline: 1.1811x; 1.0499x over previous
//
#include <hip/hip_runtime.h>

#define SEQ    2048
#define DK     64
#define QBLK   128
#define KVBLK  64
#define NTILE  (SEQ / KVBLK)   // 32
#define PITCH  72              // K/V LDS pitch (bf16), 144B rows
#define PPITCH 72              // P LDS pitch: row must hold KVBLK=64 bf16 + pad
                               // (R8 bug: 40 -> rows overlapped, absmax 1.39)

typedef __attribute__((ext_vector_type(8))) __bf16 bf16x8;
typedef __attribute__((ext_vector_type(4))) __bf16 bf16x4;
typedef __attribute__((ext_vector_type(2))) __bf16 bf16x2;
typedef __attribute__((ext_vector_type(4))) float  f32x4;
typedef __attribute__((ext_vector_type(4))) int    i32x4;

// 16-lane reductions via DPP row_ror (pure VALU, off the LDS pipe).
template<int CTRL>
__device__ __forceinline__ float dpp_ror(float v) {
  int i = __builtin_bit_cast(int, v);
  int r = __builtin_amdgcn_update_dpp(i, i, CTRL, 0xf, 0xf, false);
  return __builtin_bit_cast(float, r);
}
__device__ __forceinline__ float grp16_max(float v) {
  v = fmaxf(v, dpp_ror<0x128>(v));
  v = fmaxf(v, dpp_ror<0x124>(v));
  v = fmaxf(v, dpp_ror<0x122>(v));
  v = fmaxf(v, dpp_ror<0x121>(v));
  return v;
}
__device__ __forceinline__ float grp16_sum(float v) {
  v += dpp_ror<0x128>(v);
  v += dpp_ror<0x124>(v);
  v += dpp_ror<0x122>(v);
  v += dpp_ror<0x121>(v);
  return v;
}

// LDS-only barrier: global loads stay in flight across it.
__device__ __forceinline__ void block_sync_lds() {
  asm volatile("s_waitcnt lgkmcnt(0)" ::: "memory");
  __builtin_amdgcn_sched_barrier(0);
  __builtin_amdgcn_s_barrier();
  __builtin_amdgcn_sched_barrier(0);
}

// Flash attention. QBLK=128: 4 waves x 32 q-rows (two 16-row m-subtiles,
// processed sequentially to bound register live range). KV tiles of 64.
// Traffic rationale: QBLK=128 halves K/V re-read traffic vs 64 (512 x 1MB);
// mask loaded NONTEMPORAL so the 537MB single-use stream doesn't evict the
// K/V working set from L2.
// K staged at permuted row pi(j) = (j&15)*4 + (j>>4) so score col
// (nt*16+li) <-> kv=li*4+nt: mask loads int4, P writes b64, true-kv space;
// V staged unpermuted transposed via paired bf16x2 writes (conflict-free).
// Depth-1 register prefetch for mask/K/V; LDS-only barriers keep global
// loads in flight across sync points.
__global__ __launch_bounds__(256, 2)
void sdpa_fwd(const float* __restrict__ Q, const float* __restrict__ K,
              const float* __restrict__ V, const int* __restrict__ M,
              float* __restrict__ O)
{
  __shared__ __bf16 Klds[KVBLK][PITCH];
  __shared__ __bf16 Vt[DK][PITCH];
  __shared__ __bf16 Plds[4][32][PPITCH];

  const int tid  = threadIdx.x;
  const int w    = tid >> 6;
  const int lane = tid & 63;
  const int g    = lane >> 4;
  const int li   = lane & 15;

  // XCD-aware bijective swizzle (512 % 8 == 0)
  const int bid = blockIdx.x;
  const int blk = (bid & 7) * 64 + (bid >> 3);
  const int qb  = blk & (SEQ / QBLK - 1);   // & 15
  const int bh  = blk >> 4;                 // b*H + h

  const float* Qp = Q + (size_t)bh * SEQ * DK;
  const float* Kp = K + (size_t)bh * SEQ * DK;
  const float* Vp = V + (size_t)bh * SEQ * DK;
  const int*   Mp = M + (size_t)bh * SEQ * SEQ;
  float*       Op = O + (size_t)bh * SEQ * DK;

  const int q0 = qb * QBLK + w * 16;   // m-subtile row base: q0 + m*64

  // K staging: thread covers K row sk, cols [sd, sd+16)
  const int sk = tid >> 2;
  const int sd = (tid & 3) * 16;
  const int sj = ((sk & 3) << 4) | (sk >> 2);   // pi^{-1}(sk)
  // V staging: thread covers rows {vk, vk+1}, cols [vd, vd+8)
  const int vk = (tid & 31) * 2;
  const int vd = (tid >> 5) * 8;

  // ---- Q fragments for both m-subtiles (scale+log2e folded) ----
  bf16x8 qfrag[2][2];
  #pragma unroll
  for (int m = 0; m < 2; ++m) {
    const float qs = 0.125f * 1.44269504088896340736f;
    const float* qr = Qp + (size_t)(q0 + m * 64 + li) * DK + g * 8;
    #pragma unroll
    for (int h2 = 0; h2 < 2; ++h2) {
      f32x4 a = *(const f32x4*)(qr + h2 * 32);
      f32x4 b = *(const f32x4*)(qr + h2 * 32 + 4);
      bf16x8 f;
      #pragma unroll
      for (int e = 0; e < 4; ++e) { f[e] = (__bf16)(a[e] * qs); f[4 + e] = (__bf16)(b[e] * qs); }
      qfrag[m][h2] = f;
    }
  }

  f32x4 acc[2][4];
  #pragma unroll
  for (int m = 0; m < 2; ++m)
    #pragma unroll
    for (int c = 0; c < 4; ++c) acc[m][c] = (f32x4){0.f, 0.f, 0.f, 0.f};
  float m_r[2][4], l_r[2][4];
  #pragma unroll
  for (int m = 0; m < 2; ++m)
    #pragma unroll
    for (int r = 0; r < 4; ++r) { m_r[m][r] = -__builtin_inff(); l_r[m][r] = 0.f; }

  f32x4 kA[4], vA[4];
  i32x4 mA[8];   // depth-1 mask pipeline, 8 rows (2 m-subtiles x 4)

  // ---- prologue: K/V/mask tile 0 ----
  {
    const float* ks  = Kp + (size_t)sk * DK + sd;
    const float* vs0 = Vp + (size_t)vk * DK + vd;
    const float* vs1 = Vp + (size_t)(vk + 1) * DK + vd;
    #pragma unroll
    for (int i = 0; i < 4; ++i) kA[i] = *(const f32x4*)(ks + 4 * i);
    vA[0] = *(const f32x4*)vs0; vA[1] = *(const f32x4*)(vs0 + 4);
    vA[2] = *(const f32x4*)vs1; vA[3] = *(const f32x4*)(vs1 + 4);
    #pragma unroll
    for (int m = 0; m < 2; ++m)
      #pragma unroll
      for (int r = 0; r < 4; ++r)
        mA[m * 4 + r] = __builtin_nontemporal_load(
            (const i32x4*)(Mp + (size_t)(q0 + m * 64 + 4 * g + r) * SEQ + li * 4));
  }

  for (int kt = 0; kt < NTILE; ++kt) {
    block_sync_lds();   // WAR: prev tile's LDS reads complete

    // ---- stage regs -> LDS ----
    {
      bf16x8 klo, khi;
      #pragma unroll
      for (int e = 0; e < 4; ++e) {
        klo[e] = (__bf16)kA[0][e]; klo[4 + e] = (__bf16)kA[1][e];
        khi[e] = (__bf16)kA[2][e]; khi[4 + e] = (__bf16)kA[3][e];
      }
      *(bf16x8*)&Klds[sj][sd]     = klo;
      *(bf16x8*)&Klds[sj][sd + 8] = khi;
      #pragma unroll
      for (int j = 0; j < 4; ++j) {
        bf16x2 p0; p0[0] = (__bf16)vA[0][j]; p0[1] = (__bf16)vA[2][j];
        bf16x2 p1; p1[0] = (__bf16)vA[1][j]; p1[1] = (__bf16)vA[3][j];
        *(bf16x2*)&Vt[vd + j][vk]     = p0;
        *(bf16x2*)&Vt[vd + 4 + j][vk] = p1;
      }
    }

    const int tn = (kt + 1 < NTILE) ? kt + 1 : 0;   // clamped, branch-free

    // refill K/V regs for tile kt+1 (in flight across barriers/compute)
    {
      const float* ks  = Kp + (size_t)(tn * KVBLK + sk) * DK + sd;
      const float* vs0 = Vp + (size_t)(tn * KVBLK + vk) * DK + vd;
      const float* vs1 = Vp + (size_t)(tn * KVBLK + vk + 1) * DK + vd;
      #pragma unroll
      for (int i = 0; i < 4; ++i) kA[i] = *(const f32x4*)(ks + 4 * i);
      vA[0] = *(const f32x4*)vs0; vA[1] = *(const f32x4*)(vs0 + 4);
      vA[2] = *(const f32x4*)vs1; vA[3] = *(const f32x4*)(vs1 + 4);
    }

    block_sync_lds();   // staged tile visible; global loads still in flight

    // ---- per m-subtile: QK^T -> mask+softmax -> P write ----
    #pragma unroll
    for (int m = 0; m < 2; ++m) {
      f32x4 st[4];
      #pragma unroll
      for (int nt = 0; nt < 4; ++nt) {
        bf16x8 b0 = *(const bf16x8*)&Klds[nt * 16 + li][g * 8];
        bf16x8 b1 = *(const bf16x8*)&Klds[nt * 16 + li][32 + g * 8];
        f32x4 s = (f32x4){0.f, 0.f, 0.f, 0.f};
        s = __builtin_amdgcn_mfma_f32_16x16x32_bf16(qfrag[m][0], b0, s, 0, 0, 0);
        s = __builtin_amdgcn_mfma_f32_16x16x32_bf16(qfrag[m][1], b1, s, 0, 0, 0);
        st[nt] = s;
      }

      #pragma unroll
      for (int r = 0; r < 4; ++r) {
        i32x4 mm = mA[m * 4 + r];   // consume, then refill for tile tn
        mA[m * 4 + r] = __builtin_nontemporal_load(
            (const i32x4*)(Mp + (size_t)(q0 + m * 64 + 4 * g + r) * SEQ + tn * KVBLK + li * 4));
        float s0 = mm.x ? -1e9f : st[0][r];
        float s1 = mm.y ? -1e9f : st[1][r];
        float s2 = mm.z ? -1e9f : st[2][r];
        float s3 = mm.w ? -1e9f : st[3][r];
        float mx    = grp16_max(fmaxf(fmaxf(s0, s1), fmaxf(s2, s3)));
        float mnew  = fmaxf(m_r[m][r], mx);
        float alpha = __builtin_amdgcn_exp2f(m_r[m][r] - mnew);
        float p0 = __builtin_amdgcn_exp2f(s0 - mnew);
        float p1 = __builtin_amdgcn_exp2f(s1 - mnew);
        float p2 = __builtin_amdgcn_exp2f(s2 - mnew);
        float p3 = __builtin_amdgcn_exp2f(s3 - mnew);
        l_r[m][r] = l_r[m][r] * alpha + grp16_sum((p0 + p1) + (p2 + p3));
        m_r[m][r] = mnew;
        acc[m][0][r] *= alpha;
        acc[m][1][r] *= alpha;
        acc[m][2][r] *= alpha;
        acc[m][3][r] *= alpha;
        bf16x4 pk;
        pk[0] = (__bf16)p0; pk[1] = (__bf16)p1; pk[2] = (__bf16)p2; pk[3] = (__bf16)p3;
        *(bf16x4*)&Plds[w][m * 16 + 4 * g + r][li * 4] = pk;
      }
    }

    // wave-private P tiles: writes land before fragment reads
    asm volatile("s_waitcnt lgkmcnt(0)" ::: "memory");
    __builtin_amdgcn_sched_barrier(0);

    // ---- PV for both m-subtiles (V frags shared across m) ----
    #pragma unroll
    for (int dt = 0; dt < 4; ++dt) {
      bf16x8 v0 = *(const bf16x8*)&Vt[dt * 16 + li][g * 8];
      bf16x8 v1 = *(const bf16x8*)&Vt[dt * 16 + li][32 + g * 8];
      #pragma unroll
      for (int m = 0; m < 2; ++m) {
        bf16x8 pa0 = *(const bf16x8*)&Plds[w][m * 16 + li][g * 8];
        bf16x8 pa1 = *(const bf16x8*)&Plds[w][m * 16 + li][32 + g * 8];
        acc[m][dt] = __builtin_amdgcn_mfma_f32_16x16x32_bf16(pa0, v0, acc[m][dt], 0, 0, 0);
        acc[m][dt] = __builtin_amdgcn_mfma_f32_16x16x32_bf16(pa1, v1, acc[m][dt], 0, 0, 0);
      }
    }
  }

  // ---- epilogue (nontemporal: O is write-once) ----
  #pragma unroll
  for (int m = 0; m < 2; ++m)
    #pragma unroll
    for (int r = 0; r < 4; ++r) {
      float inv = 1.0f / l_r[m][r];
      float* orow = Op + (size_t)(q0 + m * 64 + 4 * g + r) * DK + li;
      #pragma unroll
      for (int dt = 0; dt < 4; ++dt)
        __builtin_nontemporal_store(acc[m][dt][r] * inv, &orow[dt * 16]);
    }
}

extern "C" void kernel_launch(void* const* d_in, const int* in_sizes, int n_in,
                              void* d_out, int out_size, void* d_ws, size_t ws_size,
                              hipStream_t stream) {
  const float* Q = (const float*)d_in[0];
  const float* K = (const float*)d_in[1];
  const float* V = (const float*)d_in[2];
  const int*   M = (const int*)d_in[3];
  float*       O = (float*)d_out;

  const int nblocks = 2 * 16 * (SEQ / QBLK);  // 512
  sdpa_fwd<<<nblocks, 256, 0, stream>>>(Q, K, V, M, O);
}